// Round 1
// baseline (176.585 us; speedup 1.0000x reference)
//
#include <hip/hip_runtime.h>

#define EMBED 128
#define NRBF 6
#define VOCAB 100

// ---------------------------------------------------------------------------
// Precompute kernel (tiny):
//   T1[v][d] = sum_j emb[v][j] * W_dense[j][d]           + b[d]   (bias folded)
//   T2[v][d] = sum_j emb[v][j] * W_dense[128+j][d]
//   Wc[k][d] = sum_j W_edge[k][j] * W_dense[256+j][d]
// grid = VOCAB+1 blocks x 128 threads; block VOCAB handles Wc.
// ---------------------------------------------------------------------------
__global__ __launch_bounds__(EMBED) void precompute_kernel(
    const float* __restrict__ W_edge,   // [6,128]
    const float* __restrict__ emb,      // [100,128]
    const float* __restrict__ Wd,       // [384,128]
    const float* __restrict__ b,        // [128]
    float* __restrict__ T1,             // [100,128]
    float* __restrict__ T2,             // [100,128]
    float* __restrict__ Wc)             // [6,128]
{
    const int d = threadIdx.x;
    const int v = blockIdx.x;
    if (v < VOCAB) {
        __shared__ float hrow[EMBED];
        hrow[d] = emb[v * EMBED + d];
        __syncthreads();
        float acc1 = b[d];
        float acc2 = 0.0f;
        #pragma unroll 8
        for (int j = 0; j < EMBED; ++j) {
            const float hv = hrow[j];
            acc1 += hv * Wd[j * EMBED + d];
            acc2 += hv * Wd[(EMBED + j) * EMBED + d];
        }
        T1[v * EMBED + d] = acc1;
        T2[v * EMBED + d] = acc2;
    } else {
        // Wc = W_edge @ Wd[256:384]
        #pragma unroll
        for (int k = 0; k < NRBF; ++k) {
            float acc = 0.0f;
            #pragma unroll 8
            for (int j = 0; j < EMBED; ++j)
                acc += W_edge[k * EMBED + j] * Wd[(2 * EMBED + j) * EMBED + d];
            Wc[k * EMBED + d] = acc;
        }
    }
}

// ---------------------------------------------------------------------------
// Main edge kernel: 32 threads per edge, one float4 of the 128-wide output
// per thread.  out[e] = silu(T1[z[a]] + T2[z[b]] + e_rbf[e] @ Wc)
// Memory-bound on the 307 MB output write.
// ---------------------------------------------------------------------------
__global__ __launch_bounds__(256) void edge_kernel(
    const float* __restrict__ e_rbf,   // [E,6]
    const int*   __restrict__ z,       // [N]
    const int*   __restrict__ nbr,     // [E,2]
    const float* __restrict__ T1,      // [100,128] (bias folded)
    const float* __restrict__ T2,      // [100,128]
    const float* __restrict__ Wc,      // [6,128]
    float* __restrict__ out,           // [E,128]
    int E)
{
    const int tid = blockIdx.x * blockDim.x + threadIdx.x;
    const int e = tid >> 5;          // 32 threads per edge
    if (e >= E) return;
    const int d = (tid & 31) * 4;    // float4 column offset

    const int na = nbr[2 * e + 0];
    const int nb = nbr[2 * e + 1];
    const int za = z[na];
    const int zb = z[nb];

    float4 acc = *reinterpret_cast<const float4*>(T1 + za * EMBED + d);
    const float4 t2 = *reinterpret_cast<const float4*>(T2 + zb * EMBED + d);
    acc.x += t2.x; acc.y += t2.y; acc.z += t2.z; acc.w += t2.w;

    const float* er = e_rbf + (long)e * NRBF;
    #pragma unroll
    for (int k = 0; k < NRBF; ++k) {
        const float ev = er[k];
        const float4 w = *reinterpret_cast<const float4*>(Wc + k * EMBED + d);
        acc.x += ev * w.x; acc.y += ev * w.y; acc.z += ev * w.z; acc.w += ev * w.w;
    }

    float4 r;
    r.x = acc.x / (1.0f + __expf(-acc.x));
    r.y = acc.y / (1.0f + __expf(-acc.y));
    r.z = acc.z / (1.0f + __expf(-acc.z));
    r.w = acc.w / (1.0f + __expf(-acc.w));

    *reinterpret_cast<float4*>(out + (long)e * EMBED + d) = r;
}

extern "C" void kernel_launch(void* const* d_in, const int* in_sizes, int n_in,
                              void* d_out, int out_size, void* d_ws, size_t ws_size,
                              hipStream_t stream)
{
    // Input order: e_rbf, z, nbr_list, W_edge, emb_table, W_dense, b_dense
    const float* e_rbf  = (const float*)d_in[0];
    const int*   z      = (const int*)  d_in[1];
    const int*   nbr    = (const int*)  d_in[2];
    const float* W_edge = (const float*)d_in[3];
    const float* emb    = (const float*)d_in[4];
    const float* Wd     = (const float*)d_in[5];
    const float* b      = (const float*)d_in[6];
    float* out = (float*)d_out;

    const int E = in_sizes[2] / 2;   // nbr_list is [E,2]

    // Workspace layout: T1 [100*128] | T2 [100*128] | Wc [6*128]
    float* T1 = (float*)d_ws;
    float* T2 = T1 + VOCAB * EMBED;
    float* Wc = T2 + VOCAB * EMBED;

    precompute_kernel<<<VOCAB + 1, EMBED, 0, stream>>>(W_edge, emb, Wd, b, T1, T2, Wc);

    const int threads_total = E * 32;
    const int block = 256;
    const int grid = (threads_total + block - 1) / block;
    edge_kernel<<<grid, block, 0, stream>>>(e_rbf, z, nbr, T1, T2, Wc, out, E);
}

// Round 2
// 144.319 us; speedup vs baseline: 1.2236x; 1.2236x over previous
//
#include <hip/hip_runtime.h>

#define EMBED 128
#define NRBF 6
#define VOCAB 100

// ---------------------------------------------------------------------------
// Precompute (tiny, ~5 µs):
//   T1[v][d] = sum_j emb[v][j] * W_dense[j][d]        + b[d]  (bias folded)
//   T2[v][d] = sum_j emb[v][j] * W_dense[128+j][d]
//   Wc[k][d] = sum_j W_edge[k][j] * W_dense[256+j][d]
// ---------------------------------------------------------------------------
__global__ __launch_bounds__(EMBED) void precompute_kernel(
    const float* __restrict__ W_edge,   // [6,128]
    const float* __restrict__ emb,      // [100,128]
    const float* __restrict__ Wd,       // [384,128]
    const float* __restrict__ b,        // [128]
    float* __restrict__ T1,             // [100,128]
    float* __restrict__ T2,             // [100,128]
    float* __restrict__ Wc)             // [6,128]
{
    const int d = threadIdx.x;
    const int v = blockIdx.x;
    if (v < VOCAB) {
        __shared__ float hrow[EMBED];
        hrow[d] = emb[v * EMBED + d];
        __syncthreads();
        float acc1 = b[d];
        float acc2 = 0.0f;
        #pragma unroll 8
        for (int j = 0; j < EMBED; ++j) {
            const float hv = hrow[j];
            acc1 += hv * Wd[j * EMBED + d];
            acc2 += hv * Wd[(EMBED + j) * EMBED + d];
        }
        T1[v * EMBED + d] = acc1;
        T2[v * EMBED + d] = acc2;
    } else {
        #pragma unroll
        for (int k = 0; k < NRBF; ++k) {
            float acc = 0.0f;
            #pragma unroll 8
            for (int j = 0; j < EMBED; ++j)
                acc += W_edge[k * EMBED + j] * Wd[(2 * EMBED + j) * EMBED + d];
            Wc[k * EMBED + d] = acc;
        }
    }
}

// ---------------------------------------------------------------------------
// Edge kernel: grid-stride, 32 threads/edge, one float4 column slice/thread.
//   out[e] = silu(T1[z[a]] + T2[z[b]] + e_rbf[e] @ Wc)
// Wc held in 24 VGPRs across the stride loop; e_rbf broadcast via shuffle.
// ---------------------------------------------------------------------------
__global__ __launch_bounds__(256) void edge_kernel(
    const float* __restrict__ e_rbf,   // [E,6]
    const int*   __restrict__ z,       // [N]
    const int*   __restrict__ nbr,     // [E,2]
    const float* __restrict__ T1,      // [100,128]
    const float* __restrict__ T2,      // [100,128]
    const float* __restrict__ Wc,      // [6,128]
    float* __restrict__ out,           // [E,128]
    int E)
{
    const int lane = threadIdx.x & 31;
    const int d    = lane * 4;
    const int gid0   = (blockIdx.x * blockDim.x + threadIdx.x) >> 5;
    const int gcount = (gridDim.x * blockDim.x) >> 5;

    // Hoist Wc into registers (invariant across edges)
    float4 wc0 = *reinterpret_cast<const float4*>(Wc + 0 * EMBED + d);
    float4 wc1 = *reinterpret_cast<const float4*>(Wc + 1 * EMBED + d);
    float4 wc2 = *reinterpret_cast<const float4*>(Wc + 2 * EMBED + d);
    float4 wc3 = *reinterpret_cast<const float4*>(Wc + 3 * EMBED + d);
    float4 wc4 = *reinterpret_cast<const float4*>(Wc + 4 * EMBED + d);
    float4 wc5 = *reinterpret_cast<const float4*>(Wc + 5 * EMBED + d);

    for (int e = gid0; e < E; e += gcount) {
        const int2 nn = *reinterpret_cast<const int2*>(nbr + 2 * e);
        const int za = z[nn.x];
        const int zb = z[nn.y];

        // one predicated load + shuffle broadcast for the 6 rbf values
        float ev_own = (lane < NRBF) ? e_rbf[e * NRBF + lane] : 0.0f;

        float4 acc = *reinterpret_cast<const float4*>(T1 + za * EMBED + d);
        const float4 t2 = *reinterpret_cast<const float4*>(T2 + zb * EMBED + d);
        acc.x += t2.x; acc.y += t2.y; acc.z += t2.z; acc.w += t2.w;

        const float e0 = __shfl(ev_own, 0, 32);
        const float e1 = __shfl(ev_own, 1, 32);
        const float e2 = __shfl(ev_own, 2, 32);
        const float e3 = __shfl(ev_own, 3, 32);
        const float e4 = __shfl(ev_own, 4, 32);
        const float e5 = __shfl(ev_own, 5, 32);

        acc.x += e0 * wc0.x; acc.y += e0 * wc0.y; acc.z += e0 * wc0.z; acc.w += e0 * wc0.w;
        acc.x += e1 * wc1.x; acc.y += e1 * wc1.y; acc.z += e1 * wc1.z; acc.w += e1 * wc1.w;
        acc.x += e2 * wc2.x; acc.y += e2 * wc2.y; acc.z += e2 * wc2.z; acc.w += e2 * wc2.w;
        acc.x += e3 * wc3.x; acc.y += e3 * wc3.y; acc.z += e3 * wc3.z; acc.w += e3 * wc3.w;
        acc.x += e4 * wc4.x; acc.y += e4 * wc4.y; acc.z += e4 * wc4.z; acc.w += e4 * wc4.w;
        acc.x += e5 * wc5.x; acc.y += e5 * wc5.y; acc.z += e5 * wc5.z; acc.w += e5 * wc5.w;

        // silu via fast reciprocal (1 trans op instead of precise div chain)
        float4 r;
        r.x = acc.x * __frcp_rn(1.0f + __expf(-acc.x));
        r.y = acc.y * __frcp_rn(1.0f + __expf(-acc.y));
        r.z = acc.z * __frcp_rn(1.0f + __expf(-acc.z));
        r.w = acc.w * __frcp_rn(1.0f + __expf(-acc.w));

        *reinterpret_cast<float4*>(out + (long)e * EMBED + d) = r;
    }
}

extern "C" void kernel_launch(void* const* d_in, const int* in_sizes, int n_in,
                              void* d_out, int out_size, void* d_ws, size_t ws_size,
                              hipStream_t stream)
{
    // Input order: e_rbf, z, nbr_list, W_edge, emb_table, W_dense, b_dense
    const float* e_rbf  = (const float*)d_in[0];
    const int*   z      = (const int*)  d_in[1];
    const int*   nbr    = (const int*)  d_in[2];
    const float* W_edge = (const float*)d_in[3];
    const float* emb    = (const float*)d_in[4];
    const float* Wd     = (const float*)d_in[5];
    const float* b      = (const float*)d_in[6];
    float* out = (float*)d_out;

    const int E = in_sizes[2] / 2;

    float* T1 = (float*)d_ws;
    float* T2 = T1 + VOCAB * EMBED;
    float* Wc = T2 + VOCAB * EMBED;

    precompute_kernel<<<VOCAB + 1, EMBED, 0, stream>>>(W_edge, emb, Wd, b, T1, T2, Wc);

    // Memory-bound: cap grid, grid-stride the edges. 2048 blocks = 8/CU.
    const int block = 256;
    const int grid = 2048;
    edge_kernel<<<grid, block, 0, stream>>>(e_rbf, z, nbr, T1, T2, Wc, out, E);
}

// Round 3
// 141.523 us; speedup vs baseline: 1.2477x; 1.0197x over previous
//
#include <hip/hip_runtime.h>

#define EMBED 128
#define NRBF 6
#define VOCAB 100
#define EBLOCK 1024
#define EGRID 512
// floats in the staged table region: T1 (100*128) + T2 (100*128) + Wc (6*128)
#define TABLE_F (VOCAB * EMBED * 2 + NRBF * EMBED)   // 26368 floats = 105472 B

// ---------------------------------------------------------------------------
// Precompute:
//   T1[v][d] = sum_j emb[v][j] * Wd[j][d]        + b[d]   (bias folded)
//   T2[v][d] = sum_j emb[v][j] * Wd[128+j][d]
//   Wc[k][d] = sum_j W_edge[k][j] * Wd[256+j][d]
// grid = VOCAB + NRBF blocks x 128 threads (Wc parallel over k now).
// ---------------------------------------------------------------------------
__global__ __launch_bounds__(EMBED) void precompute_kernel(
    const float* __restrict__ W_edge,   // [6,128]
    const float* __restrict__ emb,      // [100,128]
    const float* __restrict__ Wd,       // [384,128]
    const float* __restrict__ b,        // [128]
    float* __restrict__ T1,             // [100,128]
    float* __restrict__ T2,             // [100,128]
    float* __restrict__ Wc)             // [6,128]
{
    const int d = threadIdx.x;
    const int v = blockIdx.x;
    if (v < VOCAB) {
        __shared__ float hrow[EMBED];
        hrow[d] = emb[v * EMBED + d];
        __syncthreads();
        float acc1 = b[d];
        float acc2 = 0.0f;
        #pragma unroll 8
        for (int j = 0; j < EMBED; ++j) {
            const float hv = hrow[j];
            acc1 += hv * Wd[j * EMBED + d];
            acc2 += hv * Wd[(EMBED + j) * EMBED + d];
        }
        T1[v * EMBED + d] = acc1;
        T2[v * EMBED + d] = acc2;
    } else {
        const int k = v - VOCAB;
        float acc = 0.0f;
        #pragma unroll 8
        for (int j = 0; j < EMBED; ++j)
            acc += W_edge[k * EMBED + j] * Wd[(2 * EMBED + j) * EMBED + d];
        Wc[k * EMBED + d] = acc;
    }
}

// ---------------------------------------------------------------------------
// Edge kernel: tables staged in LDS (105 KB -> 1 block/CU, 16 waves/CU).
// 32 lanes per edge, one float4 column slice per lane; each group owns a
// CONTIGUOUS chunk of edges (linear 19 KB write streams, fill-like).
//   out[e] = silu(T1[z[a]] + T2[z[b]] + e_rbf[e] @ Wc)
// ---------------------------------------------------------------------------
__global__ __launch_bounds__(EBLOCK) void edge_kernel(
    const float* __restrict__ e_rbf,   // [E,6]
    const int*   __restrict__ z,       // [N]
    const int*   __restrict__ nbr,     // [E,2]
    const float* __restrict__ tables,  // T1|T2|Wc contiguous in ws
    float* __restrict__ out,           // [E,128]
    int E, int CH)
{
    extern __shared__ float smem[];
    float* T1s = smem;                       // [100*128]
    float* T2s = smem + VOCAB * EMBED;       // [100*128]
    float* Wcs = smem + 2 * VOCAB * EMBED;   // [6*128]

    // cooperative stage: 6592 float4s
    {
        const float4* src = reinterpret_cast<const float4*>(tables);
        float4* dst = reinterpret_cast<float4*>(smem);
        for (int i = threadIdx.x; i < TABLE_F / 4; i += EBLOCK)
            dst[i] = src[i];
    }
    __syncthreads();

    const int lane = threadIdx.x & 31;
    const int d    = lane * 4;
    const int gid  = (blockIdx.x * EBLOCK + threadIdx.x) >> 5;

    const int e0 = gid * CH;
    const int e1 = min(e0 + CH, E);

    // Wc from LDS into registers (invariant)
    const float4 wc0 = *reinterpret_cast<const float4*>(Wcs + 0 * EMBED + d);
    const float4 wc1 = *reinterpret_cast<const float4*>(Wcs + 1 * EMBED + d);
    const float4 wc2 = *reinterpret_cast<const float4*>(Wcs + 2 * EMBED + d);
    const float4 wc3 = *reinterpret_cast<const float4*>(Wcs + 3 * EMBED + d);
    const float4 wc4 = *reinterpret_cast<const float4*>(Wcs + 4 * EMBED + d);
    const float4 wc5 = *reinterpret_cast<const float4*>(Wcs + 5 * EMBED + d);

    #pragma unroll 4
    for (int e = e0; e < e1; ++e) {
        const int2 nn = *reinterpret_cast<const int2*>(nbr + 2 * e);
        const int za = z[nn.x];
        const int zb = z[nn.y];

        float ev_own = (lane < NRBF) ? e_rbf[e * NRBF + lane] : 0.0f;

        float4 acc = *reinterpret_cast<const float4*>(T1s + za * EMBED + d);
        const float4 t2 = *reinterpret_cast<const float4*>(T2s + zb * EMBED + d);
        acc.x += t2.x; acc.y += t2.y; acc.z += t2.z; acc.w += t2.w;

        const float f0 = __shfl(ev_own, 0, 32);
        const float f1 = __shfl(ev_own, 1, 32);
        const float f2 = __shfl(ev_own, 2, 32);
        const float f3 = __shfl(ev_own, 3, 32);
        const float f4 = __shfl(ev_own, 4, 32);
        const float f5 = __shfl(ev_own, 5, 32);

        acc.x += f0 * wc0.x; acc.y += f0 * wc0.y; acc.z += f0 * wc0.z; acc.w += f0 * wc0.w;
        acc.x += f1 * wc1.x; acc.y += f1 * wc1.y; acc.z += f1 * wc1.z; acc.w += f1 * wc1.w;
        acc.x += f2 * wc2.x; acc.y += f2 * wc2.y; acc.z += f2 * wc2.z; acc.w += f2 * wc2.w;
        acc.x += f3 * wc3.x; acc.y += f3 * wc3.y; acc.z += f3 * wc3.z; acc.w += f3 * wc3.w;
        acc.x += f4 * wc4.x; acc.y += f4 * wc4.y; acc.z += f4 * wc4.z; acc.w += f4 * wc4.w;
        acc.x += f5 * wc5.x; acc.y += f5 * wc5.y; acc.z += f5 * wc5.z; acc.w += f5 * wc5.w;

        float4 r;
        r.x = acc.x * __frcp_rn(1.0f + __expf(-acc.x));
        r.y = acc.y * __frcp_rn(1.0f + __expf(-acc.y));
        r.z = acc.z * __frcp_rn(1.0f + __expf(-acc.z));
        r.w = acc.w * __frcp_rn(1.0f + __expf(-acc.w));

        *reinterpret_cast<float4*>(out + (long)e * EMBED + d) = r;
    }
}

extern "C" void kernel_launch(void* const* d_in, const int* in_sizes, int n_in,
                              void* d_out, int out_size, void* d_ws, size_t ws_size,
                              hipStream_t stream)
{
    // Input order: e_rbf, z, nbr_list, W_edge, emb_table, W_dense, b_dense
    const float* e_rbf  = (const float*)d_in[0];
    const int*   z      = (const int*)  d_in[1];
    const int*   nbr    = (const int*)  d_in[2];
    const float* W_edge = (const float*)d_in[3];
    const float* emb    = (const float*)d_in[4];
    const float* Wd     = (const float*)d_in[5];
    const float* b      = (const float*)d_in[6];
    float* out = (float*)d_out;

    const int E = in_sizes[2] / 2;

    // Workspace: T1 | T2 | Wc contiguous (so the edge kernel stages in one pass)
    float* T1 = (float*)d_ws;
    float* T2 = T1 + VOCAB * EMBED;
    float* Wc = T2 + VOCAB * EMBED;

    precompute_kernel<<<VOCAB + NRBF, EMBED, 0, stream>>>(W_edge, emb, Wd, b, T1, T2, Wc);

    const int ngroups = EGRID * EBLOCK / 32;          // 16384
    const int CH = (E + ngroups - 1) / ngroups;       // 37
    edge_kernel<<<EGRID, EBLOCK, TABLE_F * 4, stream>>>(
        e_rbf, z, nbr, T1, out, E, CH);
}

// Round 4
// 125.746 us; speedup vs baseline: 1.4043x; 1.1255x over previous
//
#include <hip/hip_runtime.h>

#define EMBED 128
#define NRBF 6
#define VOCAB 100
#define EBLOCK 1024
#define EGRID 512
// floats in the staged table region: T1 (100*128) + T2 (100*128) + Wc (6*128)
#define TABLE_F (VOCAB * EMBED * 2 + NRBF * EMBED)   // 26368 floats = 105472 B

// ---------------------------------------------------------------------------
// Precompute:
//   T1[v][d] = sum_j emb[v][j] * Wd[j][d]        + b[d]   (bias folded)
//   T2[v][d] = sum_j emb[v][j] * Wd[128+j][d]
//   Wc[k][d] = sum_j W_edge[k][j] * Wd[256+j][d]
// ---------------------------------------------------------------------------
__global__ __launch_bounds__(EMBED) void precompute_kernel(
    const float* __restrict__ W_edge,   // [6,128]
    const float* __restrict__ emb,      // [100,128]
    const float* __restrict__ Wd,       // [384,128]
    const float* __restrict__ b,        // [128]
    float* __restrict__ T1,             // [100,128]
    float* __restrict__ T2,             // [100,128]
    float* __restrict__ Wc)             // [6,128]
{
    const int d = threadIdx.x;
    const int v = blockIdx.x;
    if (v < VOCAB) {
        __shared__ float hrow[EMBED];
        hrow[d] = emb[v * EMBED + d];
        __syncthreads();
        float acc1 = b[d];
        float acc2 = 0.0f;
        #pragma unroll 8
        for (int j = 0; j < EMBED; ++j) {
            const float hv = hrow[j];
            acc1 += hv * Wd[j * EMBED + d];
            acc2 += hv * Wd[(EMBED + j) * EMBED + d];
        }
        T1[v * EMBED + d] = acc1;
        T2[v * EMBED + d] = acc2;
    } else {
        const int k = v - VOCAB;
        float acc = 0.0f;
        #pragma unroll 8
        for (int j = 0; j < EMBED; ++j)
            acc += W_edge[k * EMBED + j] * Wd[(2 * EMBED + j) * EMBED + d];
        Wc[k * EMBED + d] = acc;
    }
}

// ---------------------------------------------------------------------------
// Edge kernel. Per 32-lane group: one edge at a time, contiguous chunk.
//   out[e] = silu(T1[z[a]] + T2[z[b]] + e_rbf[e] @ Wc)
// All cross-lane traffic removed: rbf scalars read as group-uniform
// broadcast loads; silu uses native v_exp_f32 / v_rcp_f32 only.
// ---------------------------------------------------------------------------
__global__ __launch_bounds__(EBLOCK) void edge_kernel(
    const float* __restrict__ e_rbf,   // [E,6]
    const int*   __restrict__ z,       // [N]
    const int*   __restrict__ nbr,     // [E,2]
    const float* __restrict__ tables,  // T1|T2|Wc contiguous in ws
    float* __restrict__ out,           // [E,128]
    int E, int CH)
{
    extern __shared__ float smem[];
    float* T1s = smem;                       // [100*128]
    float* T2s = smem + VOCAB * EMBED;       // [100*128]
    float* Wcs = smem + 2 * VOCAB * EMBED;   // [6*128]

    // cooperative stage: 6592 float4s from L2
    {
        const float4* src = reinterpret_cast<const float4*>(tables);
        float4* dst = reinterpret_cast<float4*>(smem);
        for (int i = threadIdx.x; i < TABLE_F / 4; i += EBLOCK)
            dst[i] = src[i];
    }
    __syncthreads();

    const int lane = threadIdx.x & 31;
    const int d    = lane * 4;
    const int gid  = (blockIdx.x * EBLOCK + threadIdx.x) >> 5;

    const int e0 = gid * CH;
    const int e1 = min(e0 + CH, E);

    // Wc from LDS into registers (invariant across edges)
    const float4 wc0 = *reinterpret_cast<const float4*>(Wcs + 0 * EMBED + d);
    const float4 wc1 = *reinterpret_cast<const float4*>(Wcs + 1 * EMBED + d);
    const float4 wc2 = *reinterpret_cast<const float4*>(Wcs + 2 * EMBED + d);
    const float4 wc3 = *reinterpret_cast<const float4*>(Wcs + 3 * EMBED + d);
    const float4 wc4 = *reinterpret_cast<const float4*>(Wcs + 4 * EMBED + d);
    const float4 wc5 = *reinterpret_cast<const float4*>(Wcs + 5 * EMBED + d);

    #pragma unroll 4
    for (int e = e0; e < e1; ++e) {
        const int2 nn = *reinterpret_cast<const int2*>(nbr + 2 * e);
        const int za = z[nn.x];
        const int zb = z[nn.y];

        // group-uniform broadcast loads of the 6 rbf scalars (8B-aligned)
        const float* er = e_rbf + (long)e * NRBF;
        const float2 f01 = *reinterpret_cast<const float2*>(er + 0);
        const float2 f23 = *reinterpret_cast<const float2*>(er + 2);
        const float2 f45 = *reinterpret_cast<const float2*>(er + 4);

        float4 acc = *reinterpret_cast<const float4*>(T1s + za * EMBED + d);
        const float4 t2 = *reinterpret_cast<const float4*>(T2s + zb * EMBED + d);
        acc.x += t2.x; acc.y += t2.y; acc.z += t2.z; acc.w += t2.w;

        acc.x += f01.x * wc0.x; acc.y += f01.x * wc0.y; acc.z += f01.x * wc0.z; acc.w += f01.x * wc0.w;
        acc.x += f01.y * wc1.x; acc.y += f01.y * wc1.y; acc.z += f01.y * wc1.z; acc.w += f01.y * wc1.w;
        acc.x += f23.x * wc2.x; acc.y += f23.x * wc2.y; acc.z += f23.x * wc2.z; acc.w += f23.x * wc2.w;
        acc.x += f23.y * wc3.x; acc.y += f23.y * wc3.y; acc.z += f23.y * wc3.z; acc.w += f23.y * wc3.w;
        acc.x += f45.x * wc4.x; acc.y += f45.x * wc4.y; acc.z += f45.x * wc4.z; acc.w += f45.x * wc4.w;
        acc.x += f45.y * wc5.x; acc.y += f45.y * wc5.y; acc.z += f45.y * wc5.z; acc.w += f45.y * wc5.w;

        // silu with native trans ops only: v_exp_f32 + v_rcp_f32
        float4 r;
        r.x = __fdividef(acc.x, 1.0f + __expf(-acc.x));
        r.y = __fdividef(acc.y, 1.0f + __expf(-acc.y));
        r.z = __fdividef(acc.z, 1.0f + __expf(-acc.z));
        r.w = __fdividef(acc.w, 1.0f + __expf(-acc.w));

        *reinterpret_cast<float4*>(out + (long)e * EMBED + d) = r;
    }
}

extern "C" void kernel_launch(void* const* d_in, const int* in_sizes, int n_in,
                              void* d_out, int out_size, void* d_ws, size_t ws_size,
                              hipStream_t stream)
{
    // Input order: e_rbf, z, nbr_list, W_edge, emb_table, W_dense, b_dense
    const float* e_rbf  = (const float*)d_in[0];
    const int*   z      = (const int*)  d_in[1];
    const int*   nbr    = (const int*)  d_in[2];
    const float* W_edge = (const float*)d_in[3];
    const float* emb    = (const float*)d_in[4];
    const float* Wd     = (const float*)d_in[5];
    const float* b      = (const float*)d_in[6];
    float* out = (float*)d_out;

    const int E = in_sizes[2] / 2;

    float* T1 = (float*)d_ws;
    float* T2 = T1 + VOCAB * EMBED;
    float* Wc = T2 + VOCAB * EMBED;

    precompute_kernel<<<VOCAB + NRBF, EMBED, 0, stream>>>(W_edge, emb, Wd, b, T1, T2, Wc);

    const int ngroups = EGRID * EBLOCK / 32;          // 16384
    const int CH = (E + ngroups - 1) / ngroups;       // 37
    edge_kernel<<<EGRID, EBLOCK, TABLE_F * 4, stream>>>(
        e_rbf, z, nbr, T1, out, E, CH);
}